// Round 13
// baseline (399.869 us; speedup 1.0000x reference)
//
#include <hip/hip_runtime.h>
#include <stdint.h>
#include <math.h>

typedef __attribute__((ext_vector_type(4))) int i32x4;
typedef __attribute__((ext_vector_type(4))) float f32x4;

#define GLD16(gp, lp)                                                     \
  __builtin_amdgcn_global_load_lds(                                       \
      (__attribute__((address_space(1))) void*)(gp),                      \
      (__attribute__((address_space(3))) void*)(lp), 16, 0, 0)

// ---------- prep W: qw = rint(clip(w*127)) -> int8, TILED fragment-major.
// Logical Wq is [8192][4096] = [qwx|qwh] per row. Output Wf stores each
// MFMA B-fragment (16 rows x 64 B) contiguously:
//   tile(jb 0..127, gate 0..3, kslice 0..63) -> 1 KB block, internal
//   layout lr*64 + colbyte (row-major sub-block).
// This makes the GEMM's per-wave B load one contiguous (lane-permuted)
// 1 KB -> fully coalesced, fixing r5/r7's 16-line-scatter failure.
__global__ void __launch_bounds__(256) k_prep_w(const float* __restrict__ wx,
                                                const float* __restrict__ wh,
                                                signed char* __restrict__ Wf) {
  int i = blockIdx.x * 256 + threadIdx.x;
  int e = i << 2;                 // byte index in logical [8192][4096]
  int row = e >> 12;
  int col = e & 4095;
  const float* src = (col < 2048) ? (wx + row * 2048 + col)
                                  : (wh + row * 2048 + (col - 2048));
  float4 v = *(const float4*)src;
  char4 o;
  o.x = (signed char)(int)rint(fmin(fmax((double)v.x * 127.0, -127.0), 127.0));
  o.y = (signed char)(int)rint(fmin(fmax((double)v.y * 127.0, -127.0), 127.0));
  o.z = (signed char)(int)rint(fmin(fmax((double)v.z * 127.0, -127.0), 127.0));
  o.w = (signed char)(int)rint(fmin(fmax((double)v.w * 127.0, -127.0), 127.0));
  int gate = row >> 11;
  int jrow = row & 2047;
  int jb   = jrow >> 4;
  int lr   = jrow & 15;
  int ksl  = col >> 6;
  int cb   = col & 63;            // char4 stays within the 64B sub-row
  size_t out = ((size_t)((jb << 2) + gate) * 64 + ksl) * 1024 + lr * 64 + cb;
  *(char4*)(Wf + out) = o;
}

// ---------- prep A: Aq[1024][12288] rows, slots 0..4 = [d4|d3|d2|d1|qx]
// (slot 5 unused; stride 12288 = r6/r10's proven layout.)
// hx ~= d1*2^-4 + d2*2^-11 + d3*2^-18 + d4*2^-25 ; residual <= 2^-26.
// 4-digit numerics validated on HW (r9/r10: absmax exactly 0.015625).
__global__ void __launch_bounds__(256) k_prep_a(const float* __restrict__ x,
                                                const float* __restrict__ hx,
                                                signed char* __restrict__ Aq) {
  int i = blockIdx.x * 256 + threadIdx.x;   // 524288 threads
  int e = i << 2;
  int b = e >> 11;
  int c = e & 2047;
  float4 xv = *(const float4*)(x + b * 2048 + c);
  float4 hv = *(const float4*)(hx + b * 2048 + c);
  float xa[4] = {xv.x, xv.y, xv.z, xv.w};
  float ha[4] = {hv.x, hv.y, hv.z, hv.w};
  char4 q4, s1, s2, s3, s4;
  signed char* qp = (signed char*)&q4;
  signed char* p1 = (signed char*)&s1;
  signed char* p2 = (signed char*)&s2;
  signed char* p3 = (signed char*)&s3;
  signed char* p4 = (signed char*)&s4;
  #pragma unroll
  for (int j = 0; j < 4; ++j) {
    qp[j] = (signed char)(int)rint(fmin(fmax((double)xa[j] * 127.0, -127.0), 127.0));
    double r = (double)ha[j];
    double d1 = rint(r * 16.0);     r -= d1 * 0x1p-4;
    double d2 = rint(r * 0x1p11);   r -= d2 * 0x1p-11;
    double d3 = rint(r * 0x1p18);   r -= d3 * 0x1p-18;
    double d4 = rint(r * 0x1p25);
    p1[j] = (signed char)(int)d1;
    p2[j] = (signed char)(int)d2;
    p3[j] = (signed char)(int)d3;
    p4[j] = (signed char)(int)d4;
  }
  size_t base = (size_t)b * 12288;
  *(char4*)(Aq + base + 0 * 2048 + c) = s4;   // phase 0 (smallest first)
  *(char4*)(Aq + base + 1 * 2048 + c) = s3;
  *(char4*)(Aq + base + 2 * 2048 + c) = s2;
  *(char4*)(Aq + base + 3 * 2048 + c) = s1;
  *(char4*)(Aq + base + 4 * 2048 + c) = q4;   // phase 4: qx
}

// ---------- fused i8 GEMM + LSTM epilogue ----------
// tile M=128, N=64 (4 gates x 16 j). 4 waves 2x2, wave tile 64x32.
// BK=128 i8; 80 flat K-iters (5 phases: d4,d3,d2,d1,qx); i32 accumulate;
// TwoSum Horner fold between digit phases (register-only); fp64 epilogue.
// Design = r12 (B-direct from tiled Wf + A-only LDS triple buffer), with
// ONE change: __launch_bounds__(256, 2) instead of (256, 3).
// r12's counters showed the (256,3) 168-register cap forced a per-iteration
// scratch spill (VGPR_Count 84, WRITE_SIZE 16 MB -> 254 MB, +75 MB FETCH,
// 239 us). (256,2) lifts the cap to 256 regs -> no spill; 2 blocks/CU is
// the same occupancy the 171.5 us r10 baseline ran at.
//  - B operand OUT of LDS: direct global->VGPR from tiled Wf (contiguous
//    1 KB per wave-load), distance 2, halves split around s0/s1 MFMA.
//    Counted waits only — no vmcnt drain (r5's poison).
//  - LDS stages A only: 3 x 16 KB triple buffer; traffic 72 -> 48 KB/iter.
// De-phased register A-prefetch retained (ds_reads between s0 and s1).
__global__ void __launch_bounds__(256, 2) k_gemm_lstm(
    const signed char* __restrict__ Aq, const signed char* __restrict__ Wf,
    const float* __restrict__ bx, const float* __restrict__ bh,
    const float* __restrict__ cx, float* __restrict__ out) {
  __shared__ __align__(16) signed char smem[49152];   // 3 x 16K A buffers

  const int t  = threadIdx.x;
  const int wv = t >> 6;
  const int ln = t & 63;
  const int wm = wv & 1;
  const int wn = wv >> 1;
  const int lr = ln & 15;
  const int q  = ln >> 4;

  const int jb = blockIdx.x;          // j0 = jb*16
  const int j0 = jb * 16;
  const int m0 = blockIdx.y * 128;

  // A staging source offsets (XOR-swizzled chunks)
  int sA[4];
  #pragma unroll
  for (int is = 0; is < 4; ++is) {
    int s = is * 256 + t;
    int r = s >> 3;
    int c = s & 7;
    int cp = c ^ (r & 7);
    sA[is] = (m0 + r) * 12288 + cp * 16;
  }

  // A LDS read offsets (s=0 half; s=1 half = offset ^ 64)
  int aoff[4];
  const int swz = lr & 7;
  #pragma unroll
  for (int mf = 0; mf < 4; ++mf)
    aoff[mf] = (wm * 64 + mf * 16 + lr) * 128 + ((q ^ swz) * 16);

  // B per-lane base pointers into tiled Wf: fragment (jb, gate=wn*2+nf, ksl)
  // lives at ((jb*4+gate)*64 + ksl)*1024; lane (q,lr) owns bytes lr*64+q*16.
  const signed char* pB[2];
  #pragma unroll
  for (int nf = 0; nf < 2; ++nf)
    pB[nf] = Wf + ((size_t)((jb << 2) + wn * 2 + nf) * 64) * 1024 + lr * 64 + q * 16;

  i32x4 acc[4][2];
  f32x4 Hh[4][2], Hl[4][2];
  #pragma unroll
  for (int mf = 0; mf < 4; ++mf)
    #pragma unroll
    for (int nf = 0; nf < 2; ++nf)
      acc[mf][nf] = (i32x4){0, 0, 0, 0};

  // named register sets (static indices only)
  i32x4 Aa[4][2], Ab[4][2];   // A frags: even-iter / odd-iter sets
  i32x4 Ba[2][2], Bb[2][2];   // B frags: even-iter / odd-iter sets

  // flat K-iteration g (0..79):
  //   kA(g) = (g>>4)*2048 + (g&15)*128
  //   B kslice(g,s) = ((g>>4)<4 ? 32:0) + (g&15)*2 + s
  // prologue: stage A(0,1,2) -> buf0,1,2; load B(0)->Ba, B(1)->Bb;
  // vmcnt(16) -> A(0) done; barrier; read A(0) frags -> Aa.
  #pragma unroll
  for (int tl = 0; tl < 3; ++tl) {
    const int kA0 = tl * 128;
    #pragma unroll
    for (int is = 0; is < 4; ++is)
      GLD16(Aq + sA[is] + kA0, smem + tl * 16384 + is * 4096 + wv * 1024);
  }
  {
    #pragma unroll
    for (int nf = 0; nf < 2; ++nf) {
      Ba[nf][0] = *(const i32x4*)(pB[nf] + (size_t)32 * 1024);
      Ba[nf][1] = *(const i32x4*)(pB[nf] + (size_t)33 * 1024);
    }
    #pragma unroll
    for (int nf = 0; nf < 2; ++nf) {
      Bb[nf][0] = *(const i32x4*)(pB[nf] + (size_t)34 * 1024);
      Bb[nf][1] = *(const i32x4*)(pB[nf] + (size_t)35 * 1024);
    }
  }
  asm volatile("s_waitcnt vmcnt(16)" ::: "memory");
  __builtin_amdgcn_s_barrier();
  __builtin_amdgcn_sched_barrier(0);
  {
    #pragma unroll
    for (int mf = 0; mf < 4; ++mf)
      #pragma unroll
      for (int s = 0; s < 2; ++s)
        Aa[mf][s] = *(const i32x4*)&smem[aoff[mf] ^ (s << 6)];
  }

  int stg = 0;        // LDS base of buffer to stage A(g+3) into (= A(g)'s buf)
  int nxt = 16384;    // LDS base of A(g+1)'s buffer (prefetch source)

#define FOLD(G)                                                            \
  if (((G) & 15) == 15) {                                                  \
    const int ph_ = (G) >> 4;                                              \
    if (ph_ == 0) {                                                        \
      _Pragma("unroll")                                                    \
      for (int mf = 0; mf < 4; ++mf)                                       \
        _Pragma("unroll")                                                  \
        for (int nf = 0; nf < 2; ++nf) {                                   \
          _Pragma("unroll")                                                \
          for (int r = 0; r < 4; ++r) {                                    \
            Hh[mf][nf][r] = (float)acc[mf][nf][r];                         \
            Hl[mf][nf][r] = 0.f;                                           \
          }                                                                \
          acc[mf][nf] = (i32x4){0, 0, 0, 0};                               \
        }                                                                  \
    } else if (ph_ < 4) {                                                  \
      _Pragma("unroll")                                                    \
      for (int mf = 0; mf < 4; ++mf)                                       \
        _Pragma("unroll")                                                  \
        for (int nf = 0; nf < 2; ++nf) {                                   \
          _Pragma("unroll")                                                \
          for (int r = 0; r < 4; ++r) {                                    \
            float tv = Hh[mf][nf][r] * 0x1p-7f;   /* exact (pow2) */       \
            float S  = (float)acc[mf][nf][r];     /* exact (|S|<2^20) */   \
            float sm = tv + S;                                             \
            float z  = sm - tv;                                            \
            float e  = (tv - (sm - z)) + (S - z);                          \
            Hl[mf][nf][r] = Hl[mf][nf][r] * 0x1p-7f + e;                   \
            Hh[mf][nf][r] = sm;                                            \
          }                                                                \
          acc[mf][nf] = (i32x4){0, 0, 0, 0};                               \
        }                                                                  \
    }                                                                      \
  }

// KBODY: s0 MFMA -> vmcnt(VMC) -> barrier -> stage A(G+3) -> load B(G+2)[0]
//        -> ds_read A(G+1) -> s1 MFMA -> load B(G+2)[1] -> fold.
#define KBODY(G, AC, BC, AN, DO_STAGE, DO_LOADB, DO_PREF, VMC) do {        \
    _Pragma("unroll")                                                      \
    for (int mf = 0; mf < 4; ++mf)                                         \
      _Pragma("unroll")                                                    \
      for (int nf = 0; nf < 2; ++nf)                                       \
        acc[mf][nf] = __builtin_amdgcn_mfma_i32_16x16x64_i8(               \
            AC[mf][0], BC[nf][0], acc[mf][nf], 0, 0, 0);                   \
    __builtin_amdgcn_sched_barrier(0);                                     \
    asm volatile("s_waitcnt vmcnt(" #VMC ")" ::: "memory");                \
    __builtin_amdgcn_s_barrier();   /* raw barrier: no vmcnt drain */      \
    __builtin_amdgcn_sched_barrier(0);                                     \
    const int gn_  = (G) + 3;                                              \
    const int gb_  = (G) + 2;                                              \
    const int kAn_ = (gn_ >> 4) * 2048 + ((gn_ & 15) << 7);                \
    const int ks0_ = (((gb_ >> 4) < 4) ? 32 : 0) + ((gb_ & 15) << 1);      \
    if (DO_STAGE) {                                                        \
      _Pragma("unroll")                                                    \
      for (int is = 0; is < 4; ++is)                                       \
        GLD16(Aq + sA[is] + kAn_, smem + stg + is * 4096 + wv * 1024);     \
    }                                                                      \
    if (DO_LOADB) {  /* s0-halves of B(G+2) into regs s0 just freed */     \
      BC[0][0] = *(const i32x4*)(pB[0] + (size_t)ks0_ * 1024);             \
      BC[1][0] = *(const i32x4*)(pB[1] + (size_t)ks0_ * 1024);             \
    }                                                                      \
    if (DO_PREF) {   /* A(G+1) frags; latency hides under s1 */            \
      _Pragma("unroll")                                                    \
      for (int mf = 0; mf < 4; ++mf)                                       \
        _Pragma("unroll")                                                  \
        for (int s = 0; s < 2; ++s)                                        \
          AN[mf][s] = *(const i32x4*)&smem[nxt + (aoff[mf] ^ (s << 6))];   \
    }                                                                      \
    __builtin_amdgcn_sched_barrier(0);                                     \
    _Pragma("unroll")                                                      \
    for (int mf = 0; mf < 4; ++mf)                                         \
      _Pragma("unroll")                                                    \
      for (int nf = 0; nf < 2; ++nf)                                       \
        acc[mf][nf] = __builtin_amdgcn_mfma_i32_16x16x64_i8(               \
            AC[mf][1], BC[nf][1], acc[mf][nf], 0, 0, 0);                   \
    if (DO_LOADB) {  /* s1-halves after s1 consumed old values */          \
      BC[0][1] = *(const i32x4*)(pB[0] + (size_t)(ks0_ + 1) * 1024);       \
      BC[1][1] = *(const i32x4*)(pB[1] + (size_t)(ks0_ + 1) * 1024);       \
    }                                                                      \
    FOLD(G);                                                               \
    stg += 16384; if (stg == 49152) stg = 0;                               \
    nxt += 16384; if (nxt == 49152) nxt = 0;                               \
  } while (0)

  #pragma unroll 1
  for (int g = 0; g < 76; g += 2) {
    KBODY(g,     Aa, Ba, Ab, 1, 1, 1, 10);
    KBODY(g + 1, Ab, Bb, Aa, 1, 1, 1, 10);
  }
  KBODY(76, Aa, Ba, Ab, 1, 1, 1, 10);   // stages A(79), loads B(78)
  KBODY(77, Ab, Bb, Aa, 0, 1, 1, 10);   // loads B(79)
  KBODY(78, Aa, Ba, Ab, 0, 0, 1, 6);    // prefetch A(79)
  KBODY(79, Ab, Bb, Aa, 0, 0, 0, 0);    // final tile, regs only
#undef KBODY
#undef FOLD
  // acc = exact Sx (i32); Hh+Hl = S_d1 + S_d2*2^-7 + S_d3*2^-14 + S_d4*2^-21

  const double invsq = 1.0 / 16129.0;     // 1/127^2
  const double hsc   = 0x1p-4 / 127.0;    // digit-chain scale

  float (*Lgo)[128][17] = (float(*)[128][17])smem;   // overlay on staging LDS

  __syncthreads();
  if (wn == 1) {   // gates g (nf=0), o (nf=1): activate, stash q*127 ints
    #pragma unroll
    for (int mf = 0; mf < 4; ++mf) {
      #pragma unroll
      for (int nf = 0; nf < 2; ++nf) {
        int gate = 2 + nf;
        int gcol = gate * 2048 + j0 + lr;
        double bsum = (double)bx[gcol] + (double)bh[gcol];
        #pragma unroll
        for (int r = 0; r < 4; ++r) {
          double Sx = (double)acc[mf][nf][r];
          double Hd = ((double)Hh[mf][nf][r] + (double)Hl[mf][nf][r]) * hsc;
          double pre = Sx * invsq + Hd + bsum;
          double av = (gate == 2) ? tanh(pre) : (1.0 / (1.0 + exp(-pre)));
          double qv = rint(fmin(fmax(av * 127.0, -127.0), 127.0));
          int m = wm * 64 + mf * 16 + q * 4 + r;
          Lgo[nf][m][lr] = (float)qv;
        }
      }
    }
  }
  __syncthreads();
  if (wn == 0) {   // gates f (nf=0), i (nf=1): combine + store
    #pragma unroll
    for (int mf = 0; mf < 4; ++mf) {
      int gcf = j0 + lr;
      int gci = 2048 + j0 + lr;
      double bf_ = (double)bx[gcf] + (double)bh[gcf];
      double bi_ = (double)bx[gci] + (double)bh[gci];
      #pragma unroll
      for (int r = 0; r < 4; ++r) {
        int m = wm * 64 + mf * 16 + q * 4 + r;
        double fpre = (double)acc[mf][0][r] * invsq +
                      ((double)Hh[mf][0][r] + (double)Hl[mf][0][r]) * hsc + bf_;
        double ipre = (double)acc[mf][1][r] * invsq +
                      ((double)Hh[mf][1][r] + (double)Hl[mf][1][r]) * hsc + bi_;
        double fs = 1.0 / (1.0 + exp(-fpre));
        double is = 1.0 / (1.0 + exp(-ipre));
        double fv = rint(fmin(fmax(fs * 127.0, -127.0), 127.0)) / 127.0;
        double iv = rint(fmin(fmax(is * 127.0, -127.0), 127.0)) / 127.0;
        double gv = (double)Lgo[0][m][lr] / 127.0;
        double ov = (double)Lgo[1][m][lr] / 127.0;
        int row = m0 + m;
        int col = j0 + lr;
        double cn = fv * (double)cx[row * 2048 + col] + iv * gv;
        double tq = rint(fmin(fmax(tanh(cn) * 127.0, -127.0), 127.0)) / 127.0;
        double hv = ov * tq;
        double cq = rint(fmin(fmax(cn * 127.0, -127.0), 127.0)) / 127.0;
        out[row * 2048 + col] = (float)hv;
        out[2097152 + row * 2048 + col] = (float)cq;
      }
    }
  }
}

// ---------- launch ----------
extern "C" void kernel_launch(void* const* d_in, const int* in_sizes, int n_in,
                              void* d_out, int out_size, void* d_ws, size_t ws_size,
                              hipStream_t stream) {
  const float* x  = (const float*)d_in[0];
  const float* hx = (const float*)d_in[1];
  const float* cx = (const float*)d_in[2];
  const float* wx = (const float*)d_in[3];
  const float* bx = (const float*)d_in[4];
  const float* wh = (const float*)d_in[5];
  const float* bh = (const float*)d_in[6];
  float* out = (float*)d_out;

  signed char* Wf = (signed char*)d_ws;                       // 33,554,432 B
  signed char* Aq = (signed char*)d_ws + 33554432;            // 12,582,912 B

  k_prep_w<<<dim3(32768), dim3(256), 0, stream>>>(wx, wh, Wf);
  k_prep_a<<<dim3(2048), dim3(256), 0, stream>>>(x, hx, Aq);
  k_gemm_lstm<<<dim3(128, 8), dim3(256), 0, stream>>>(Aq, Wf, bx, bh, cx, out);
}

// Round 14
// 327.641 us; speedup vs baseline: 1.2204x; 1.2204x over previous
//
#include <hip/hip_runtime.h>
#include <stdint.h>
#include <math.h>

typedef __attribute__((ext_vector_type(4))) int i32x4;
typedef __attribute__((ext_vector_type(4))) float f32x4;

#define GLD16(gp, lp)                                                     \
  __builtin_amdgcn_global_load_lds(                                       \
      (__attribute__((address_space(1))) void*)(gp),                      \
      (__attribute__((address_space(3))) void*)(lp), 16, 0, 0)

// ---------- fused prep (one launch): blocks [0,32768) quantize W,
// blocks [32768,34816) decompose x/hx. Both memory-bound & independent;
// merging removes one launch serialization and overlaps them.
//
// W path: qw = rint(clip(w*127)) -> int8, Wq[8192][4096] = [qwx|qwh].
// A path: Aq[1024][12288] rows, slots 0..4 = [d4|d3|d2|d1|qx]
//   hx ~= d1*2^-4 + d2*2^-11 + d3*2^-18 + d4*2^-25 ; residual <= 2^-26.
//   4-digit truncation adds ~5e-9 rms to pre-activations, ~30x below the
//   fp32 reference's own einsum noise; HW-validated r9/r10 (absmax
//   exactly 0.015625). Stride 12288 (slot 5 unused) = r6/r10 proven layout.
__global__ void __launch_bounds__(256) k_prep(const float* __restrict__ wx,
                                              const float* __restrict__ wh,
                                              const float* __restrict__ x,
                                              const float* __restrict__ hx,
                                              signed char* __restrict__ Wq,
                                              signed char* __restrict__ Aq) {
  if (blockIdx.x < 32768) {
    int i = blockIdx.x * 256 + threadIdx.x;
    int e = i << 2;
    int g = e >> 12;
    int c = e & 4095;
    const float* src = (c < 2048) ? (wx + g * 2048 + c) : (wh + g * 2048 + (c - 2048));
    float4 v = *(const float4*)src;
    char4 o;
    o.x = (signed char)(int)rint(fmin(fmax((double)v.x * 127.0, -127.0), 127.0));
    o.y = (signed char)(int)rint(fmin(fmax((double)v.y * 127.0, -127.0), 127.0));
    o.z = (signed char)(int)rint(fmin(fmax((double)v.z * 127.0, -127.0), 127.0));
    o.w = (signed char)(int)rint(fmin(fmax((double)v.w * 127.0, -127.0), 127.0));
    *(char4*)(Wq + e) = o;
  } else {
    int i = (blockIdx.x - 32768) * 256 + threadIdx.x;   // 524288 threads
    int e = i << 2;
    int b = e >> 11;
    int c = e & 2047;
    float4 xv = *(const float4*)(x + b * 2048 + c);
    float4 hv = *(const float4*)(hx + b * 2048 + c);
    float xa[4] = {xv.x, xv.y, xv.z, xv.w};
    float ha[4] = {hv.x, hv.y, hv.z, hv.w};
    char4 q4, s1, s2, s3, s4;
    signed char* qp = (signed char*)&q4;
    signed char* p1 = (signed char*)&s1;
    signed char* p2 = (signed char*)&s2;
    signed char* p3 = (signed char*)&s3;
    signed char* p4 = (signed char*)&s4;
    #pragma unroll
    for (int j = 0; j < 4; ++j) {
      qp[j] = (signed char)(int)rint(fmin(fmax((double)xa[j] * 127.0, -127.0), 127.0));
      double r = (double)ha[j];
      double d1 = rint(r * 16.0);     r -= d1 * 0x1p-4;
      double d2 = rint(r * 0x1p11);   r -= d2 * 0x1p-11;
      double d3 = rint(r * 0x1p18);   r -= d3 * 0x1p-18;
      double d4 = rint(r * 0x1p25);
      p1[j] = (signed char)(int)d1;
      p2[j] = (signed char)(int)d2;
      p3[j] = (signed char)(int)d3;
      p4[j] = (signed char)(int)d4;
    }
    size_t base = (size_t)b * 12288;
    *(char4*)(Aq + base + 0 * 2048 + c) = s4;   // phase 0 (smallest first)
    *(char4*)(Aq + base + 1 * 2048 + c) = s3;
    *(char4*)(Aq + base + 2 * 2048 + c) = s2;
    *(char4*)(Aq + base + 3 * 2048 + c) = s1;
    *(char4*)(Aq + base + 4 * 2048 + c) = q4;   // phase 4: qx
  }
}

// ---------- fused i8 GEMM + LSTM epilogue (r10 kernel, verbatim) ----------
// tile M=128, N=64 (4 gates x 16 j). 4 waves 2x2, wave tile 64x32.
// BK=128 i8; 80 flat K-iters (5 phases: d4,d3,d2,d1,qx); i32 accumulate;
// TwoSum Horner fold between digit phases (register-only); fp64 epilogue.
// Structure (measured 171.5 us GEMM, best of 13 rounds): A and B staged via
// GLD16 into a 3 x 24 KB triple buffer; each wave holds tile g's 12
// fragments in REGISTERS (two named sets, unroll-2 swap) and prefetches
// tile g+1's fragments from LDS during iter g:
//   MFMA s0 (regs) -> vmcnt(6) -> s_barrier -> stage(g+3 -> freed buf)
//   + ds_read(g+1 -> other reg set) -> MFMA s1 (regs) -> fold
// One barrier/iter; counted vmcnt never drains in the main loop.
// LESSONS (kept as constraints):
//  - B must flow through GLD16. Per-wave B register loads (r5/r7/r13:
//    scatter / distance-2 / coalesced-tiled, spill-free) all regress 70-90%:
//    the dependent load->MFMA edge in the in-order vmcnt queue serializes
//    every barrier iteration on L2 latency.
//  - (256,3) launch bound spills ~3 dwords/thread/iter (r12: WRITE_SIZE
//    16->254 MB). Keep (256,2).
__global__ void __launch_bounds__(256, 2) k_gemm_lstm(
    const signed char* __restrict__ Aq, const signed char* __restrict__ Wq,
    const float* __restrict__ bx, const float* __restrict__ bh,
    const float* __restrict__ cx, float* __restrict__ out) {
  __shared__ __align__(16) signed char smem[73728];   // 3 x (16K A + 8K B)

  const int t  = threadIdx.x;
  const int wv = t >> 6;
  const int ln = t & 63;
  const int wm = wv & 1;
  const int wn = wv >> 1;
  const int lr = ln & 15;
  const int q  = ln >> 4;

  const int j0 = blockIdx.x * 16;
  const int m0 = blockIdx.y * 128;

  // staging source offsets (XOR-swizzled chunks)
  int sA[4];
  #pragma unroll
  for (int is = 0; is < 4; ++is) {
    int s = is * 256 + t;
    int r = s >> 3;
    int c = s & 7;
    int cp = c ^ (r & 7);
    sA[is] = (m0 + r) * 12288 + cp * 16;
  }
  int sB[2];
  #pragma unroll
  for (int is = 0; is < 2; ++is) {
    int s = is * 256 + t;
    int r = s >> 3;
    int c = s & 7;
    int cp = c ^ (r & 7);
    int wrow = (r >> 4) * 2048 + j0 + (r & 15);   // gate*2048 + j
    sB[is] = wrow * 4096 + cp * 16;
  }

  // LDS read offsets (s=0 half; s=1 half = offset ^ 64)
  int aoff[4], boff[2];
  const int swz = lr & 7;
  #pragma unroll
  for (int mf = 0; mf < 4; ++mf)
    aoff[mf] = (wm * 64 + mf * 16 + lr) * 128 + ((q ^ swz) * 16);
  #pragma unroll
  for (int nf = 0; nf < 2; ++nf)
    boff[nf] = (wn * 32 + nf * 16 + lr) * 128 + ((q ^ swz) * 16);

  i32x4 acc[4][2];
  f32x4 Hh[4][2], Hl[4][2];
  #pragma unroll
  for (int mf = 0; mf < 4; ++mf)
    #pragma unroll
    for (int nf = 0; nf < 2; ++nf)
      acc[mf][nf] = (i32x4){0, 0, 0, 0};

  // two named fragment sets (all indices static -> stay in VGPRs)
  i32x4 Aa[4][2], Ba[2][2];   // even iters current
  i32x4 Ab[4][2], Bb[2][2];   // odd iters current

  // flat K-iteration g (0..79):  kA(g) = (g>>4)*2048 + (g&15)*128
  //                              kB(g) = ((g>>4)<4 ? 2048:0) + (g&15)*128
  // prologue: stage tiles 0,1,2 into b0,b1,b2; vmcnt(12) -> tile0 done;
  // barrier; read tile0 fragments into set A.
  #pragma unroll
  for (int tl = 0; tl < 3; ++tl) {
    const int kA0 = tl * 128;
    const int kB0 = 2048 + tl * 128;
    #pragma unroll
    for (int is = 0; is < 4; ++is)
      GLD16(Aq + sA[is] + kA0, smem + tl * 24576 + is * 4096 + wv * 1024);
    #pragma unroll
    for (int is = 0; is < 2; ++is)
      GLD16(Wq + sB[is] + kB0, smem + tl * 24576 + 16384 + is * 4096 + wv * 1024);
  }
  asm volatile("s_waitcnt vmcnt(12)" ::: "memory");
  __builtin_amdgcn_s_barrier();
  __builtin_amdgcn_sched_barrier(0);
  {
    const signed char* As_ = smem;
    const signed char* Bs_ = smem + 16384;
    #pragma unroll
    for (int mf = 0; mf < 4; ++mf)
      #pragma unroll
      for (int s = 0; s < 2; ++s)
        Aa[mf][s] = *(const i32x4*)&As_[aoff[mf] ^ (s << 6)];
    #pragma unroll
    for (int nf = 0; nf < 2; ++nf)
      #pragma unroll
      for (int s = 0; s < 2; ++s)
        Ba[nf][s] = *(const i32x4*)&Bs_[boff[nf] ^ (s << 6)];
  }

  int stg = 0;        // LDS base of buffer to stage tile g+3 into
  int nxt = 24576;    // LDS base of tile g+1's buffer (prefetch source)

#define FOLD(G)                                                            \
  if (((G) & 15) == 15) {                                                  \
    const int ph_ = (G) >> 4;                                              \
    if (ph_ == 0) {                                                        \
      _Pragma("unroll")                                                    \
      for (int mf = 0; mf < 4; ++mf)                                       \
        _Pragma("unroll")                                                  \
        for (int nf = 0; nf < 2; ++nf) {                                   \
          _Pragma("unroll")                                                \
          for (int r = 0; r < 4; ++r) {                                    \
            Hh[mf][nf][r] = (float)acc[mf][nf][r];                         \
            Hl[mf][nf][r] = 0.f;                                           \
          }                                                                \
          acc[mf][nf] = (i32x4){0, 0, 0, 0};                               \
        }                                                                  \
    } else if (ph_ < 4) {                                                  \
      _Pragma("unroll")                                                    \
      for (int mf = 0; mf < 4; ++mf)                                       \
        _Pragma("unroll")                                                  \
        for (int nf = 0; nf < 2; ++nf) {                                   \
          _Pragma("unroll")                                                \
          for (int r = 0; r < 4; ++r) {                                    \
            float tv = Hh[mf][nf][r] * 0x1p-7f;   /* exact (pow2) */       \
            float S  = (float)acc[mf][nf][r];     /* exact (|S|<2^20) */   \
            float sm = tv + S;                                             \
            float z  = sm - tv;                                            \
            float e  = (tv - (sm - z)) + (S - z);                          \
            Hl[mf][nf][r] = Hl[mf][nf][r] * 0x1p-7f + e;                   \
            Hh[mf][nf][r] = sm;                                            \
          }                                                                \
          acc[mf][nf] = (i32x4){0, 0, 0, 0};                               \
        }                                                                  \
    }                                                                      \
  }

#define KBODY(G, AC, BC, AN, BN, DO_STAGE, DO_PREF, VMC) do {              \
    /* s0 MFMAs: pure registers */                                         \
    _Pragma("unroll")                                                      \
    for (int mf = 0; mf < 4; ++mf)                                         \
      _Pragma("unroll")                                                    \
      for (int nf = 0; nf < 2; ++nf)                                       \
        acc[mf][nf] = __builtin_amdgcn_mfma_i32_16x16x64_i8(               \
            AC[mf][0], BC[nf][0], acc[mf][nf], 0, 0, 0);                   \
    __builtin_amdgcn_sched_barrier(0);                                     \
    asm volatile("s_waitcnt vmcnt(" #VMC ")" ::: "memory");                \
    __builtin_amdgcn_s_barrier();   /* raw barrier: no vmcnt drain */      \
    __builtin_amdgcn_sched_barrier(0);                                     \
    if (DO_STAGE) { /* stage tile G+3 into the buffer tile G vacated */    \
      const int gn_  = (G) + 3;                                            \
      const int kAn_ = (gn_ >> 4) * 2048 + ((gn_ & 15) << 7);              \
      const int kBn_ = (((gn_ >> 4) < 4) ? 2048 : 0) + ((gn_ & 15) << 7);  \
      _Pragma("unroll")                                                    \
      for (int is = 0; is < 4; ++is)                                       \
        GLD16(Aq + sA[is] + kAn_, smem + stg + is * 4096 + wv * 1024);     \
      _Pragma("unroll")                                                    \
      for (int is = 0; is < 2; ++is)                                       \
        GLD16(Wq + sB[is] + kBn_,                                          \
              smem + stg + 16384 + is * 4096 + wv * 1024);                 \
    }                                                                      \
    if (DO_PREF) { /* read tile G+1 fragments into the other reg set */    \
      const signed char* As_ = smem + nxt;                                 \
      const signed char* Bs_ = smem + nxt + 16384;                         \
      _Pragma("unroll")                                                    \
      for (int mf = 0; mf < 4; ++mf)                                       \
        _Pragma("unroll")                                                  \
        for (int s = 0; s < 2; ++s)                                        \
          AN[mf][s] = *(const i32x4*)&As_[aoff[mf] ^ (s << 6)];            \
      _Pragma("unroll")                                                    \
      for (int nf = 0; nf < 2; ++nf)                                       \
        _Pragma("unroll")                                                  \
        for (int s = 0; s < 2; ++s)                                        \
          BN[nf][s] = *(const i32x4*)&Bs_[boff[nf] ^ (s << 6)];            \
    }                                                                      \
    __builtin_amdgcn_sched_barrier(0);                                     \
    /* s1 MFMAs: pure registers (LDS latency hides under these) */         \
    _Pragma("unroll")                                                      \
    for (int mf = 0; mf < 4; ++mf)                                         \
      _Pragma("unroll")                                                    \
      for (int nf = 0; nf < 2; ++nf)                                       \
        acc[mf][nf] = __builtin_amdgcn_mfma_i32_16x16x64_i8(               \
            AC[mf][1], BC[nf][1], acc[mf][nf], 0, 0, 0);                   \
    FOLD(G);                                                               \
    stg += 24576; if (stg == 73728) stg = 0;                               \
    nxt += 24576; if (nxt == 73728) nxt = 0;                               \
  } while (0)

  #pragma unroll 1
  for (int g = 0; g < 76; g += 2) {
    KBODY(g,     Aa, Ba, Ab, Bb, 1, 1, 6);
    KBODY(g + 1, Ab, Bb, Aa, Ba, 1, 1, 6);
  }
  KBODY(76, Aa, Ba, Ab, Bb, 1, 1, 6);   // stages tile 79 (last)
  KBODY(77, Ab, Bb, Aa, Ba, 0, 1, 6);   // outstanding 78,79 -> wait 78
  KBODY(78, Aa, Ba, Ab, Bb, 0, 1, 0);   // drain tile 79, read it
  KBODY(79, Ab, Bb, Aa, Ba, 0, 0, 0);   // final tile, regs only
#undef KBODY
#undef FOLD
  // acc = exact Sx (i32); Hh+Hl = S_d1 + S_d2*2^-7 + S_d3*2^-14 + S_d4*2^-21

  const double invsq = 1.0 / 16129.0;     // 1/127^2
  const double hsc   = 0x1p-4 / 127.0;    // digit-chain scale

  float (*Lgo)[128][17] = (float(*)[128][17])smem;   // overlay on staging LDS

  __syncthreads();
  if (wn == 1) {   // gates g (nf=0), o (nf=1): activate, stash q*127 ints
    #pragma unroll
    for (int mf = 0; mf < 4; ++mf) {
      #pragma unroll
      for (int nf = 0; nf < 2; ++nf) {
        int gate = 2 + nf;
        int gcol = gate * 2048 + j0 + lr;
        double bsum = (double)bx[gcol] + (double)bh[gcol];
        #pragma unroll
        for (int r = 0; r < 4; ++r) {
          double Sx = (double)acc[mf][nf][r];
          double Hd = ((double)Hh[mf][nf][r] + (double)Hl[mf][nf][r]) * hsc;
          double pre = Sx * invsq + Hd + bsum;
          double av = (gate == 2) ? tanh(pre) : (1.0 / (1.0 + exp(-pre)));
          double qv = rint(fmin(fmax(av * 127.0, -127.0), 127.0));
          int m = wm * 64 + mf * 16 + q * 4 + r;
          Lgo[nf][m][lr] = (float)qv;
        }
      }
    }
  }
  __syncthreads();
  if (wn == 0) {   // gates f (nf=0), i (nf=1): combine + store
    #pragma unroll
    for (int mf = 0; mf < 4; ++mf) {
      int gcf = j0 + lr;
      int gci = 2048 + j0 + lr;
      double bf_ = (double)bx[gcf] + (double)bh[gcf];
      double bi_ = (double)bx[gci] + (double)bh[gci];
      #pragma unroll
      for (int r = 0; r < 4; ++r) {
        int m = wm * 64 + mf * 16 + q * 4 + r;
        double fpre = (double)acc[mf][0][r] * invsq +
                      ((double)Hh[mf][0][r] + (double)Hl[mf][0][r]) * hsc + bf_;
        double ipre = (double)acc[mf][1][r] * invsq +
                      ((double)Hh[mf][1][r] + (double)Hl[mf][1][r]) * hsc + bi_;
        double fs = 1.0 / (1.0 + exp(-fpre));
        double is = 1.0 / (1.0 + exp(-ipre));
        double fv = rint(fmin(fmax(fs * 127.0, -127.0), 127.0)) / 127.0;
        double iv = rint(fmin(fmax(is * 127.0, -127.0), 127.0)) / 127.0;
        double gv = (double)Lgo[0][m][lr] / 127.0;
        double ov = (double)Lgo[1][m][lr] / 127.0;
        int row = m0 + m;
        int col = j0 + lr;
        double cn = fv * (double)cx[row * 2048 + col] + iv * gv;
        double tq = rint(fmin(fmax(tanh(cn) * 127.0, -127.0), 127.0)) / 127.0;
        double hv = ov * tq;
        double cq = rint(fmin(fmax(cn * 127.0, -127.0), 127.0)) / 127.0;
        out[row * 2048 + col] = (float)hv;
        out[2097152 + row * 2048 + col] = (float)cq;
      }
    }
  }
}

// ---------- launch ----------
extern "C" void kernel_launch(void* const* d_in, const int* in_sizes, int n_in,
                              void* d_out, int out_size, void* d_ws, size_t ws_size,
                              hipStream_t stream) {
  const float* x  = (const float*)d_in[0];
  const float* hx = (const float*)d_in[1];
  const float* cx = (const float*)d_in[2];
  const float* wx = (const float*)d_in[3];
  const float* bx = (const float*)d_in[4];
  const float* wh = (const float*)d_in[5];
  const float* bh = (const float*)d_in[6];
  float* out = (float*)d_out;

  signed char* Wq = (signed char*)d_ws;                       // 33,554,432 B
  signed char* Aq = (signed char*)d_ws + 33554432;            // 12,582,912 B

  k_prep<<<dim3(34816), dim3(256), 0, stream>>>(wx, wh, x, hx, Wq, Aq);
  k_gemm_lstm<<<dim3(128, 8), dim3(256), 0, stream>>>(Aq, Wq, bx, bh, cx, out);
}